// Round 1
// baseline (76.182 us; speedup 1.0000x reference)
//
#include <hip/hip_runtime.h>

// Cutout: out[b,c,y,x] = img[b,c,y,x] * keep(b,y,x)
// keep = no active hole rectangle covers (y,x).
// B=64, C=3, H=512, W=512, MAX_HOLES=5 (num_holes in [0,5))

#define BB 64
#define CC 3
#define HH 512
#define WW 512
#define KK 5
#define W4 (WW / 4)              // 128 float4 per row
#define PLANE4 (HH * W4)         // 65536 float4 per (b,c) plane

__global__ __launch_bounds__(256) void cutout_kernel(
    const float4* __restrict__ img,
    const int* __restrict__ num_holes,
    const int* __restrict__ ys,
    const int* __restrict__ xs,
    const int* __restrict__ hs,
    const int* __restrict__ ws,
    float4* __restrict__ out)
{
    int idx = blockIdx.x * blockDim.x + threadIdx.x;
    // total threads = B * H * W4 = 64 * 512 * 128 = 4194304
    if (idx >= BB * HH * W4) return;

    int b   = idx >> 16;          // / (H*W4) = / 65536
    int rem = idx & 65535;
    int y   = rem >> 7;           // / W4
    int xq  = rem & 127;          // float4 index within row
    int x0  = xq << 2;            // first pixel x of this quad

    int n = num_holes[b];         // wave-uniform (whole wave shares b)

    bool k0 = true, k1 = true, k2 = true, k3 = true;
    for (int k = 0; k < n; ++k) { // n <= 4, wave-uniform loop
        int yc = ys[b * KK + k];
        int xc = xs[b * KK + k];
        int hh = hs[b * KK + k];
        int wv = ws[b * KK + k];
        int y1 = max(0, yc - hh / 2);
        int y2 = min(HH, yc + hh / 2);
        if (y >= y1 && y < y2) {
            int x1 = max(0, xc - wv / 2);
            int x2 = min(WW, xc + wv / 2);
            k0 = k0 && !((x0 + 0) >= x1 && (x0 + 0) < x2);
            k1 = k1 && !((x0 + 1) >= x1 && (x0 + 1) < x2);
            k2 = k2 && !((x0 + 2) >= x1 && (x0 + 2) < x2);
            k3 = k3 && !((x0 + 3) >= x1 && (x0 + 3) < x2);
        }
    }
    float m0 = k0 ? 1.0f : 0.0f;
    float m1 = k1 ? 1.0f : 0.0f;
    float m2 = k2 ? 1.0f : 0.0f;
    float m3 = k3 ? 1.0f : 0.0f;

    // base float4 index for (b, c=0, y, xq)
    size_t p = (size_t)b * (CC * PLANE4) + (size_t)y * W4 + xq;
#pragma unroll
    for (int c = 0; c < CC; ++c) {
        float4 v = img[p + (size_t)c * PLANE4];
        v.x *= m0; v.y *= m1; v.z *= m2; v.w *= m3;
        out[p + (size_t)c * PLANE4] = v;
    }
}

extern "C" void kernel_launch(void* const* d_in, const int* in_sizes, int n_in,
                              void* d_out, int out_size, void* d_ws, size_t ws_size,
                              hipStream_t stream) {
    const float4* img      = (const float4*)d_in[0];
    const int* num_holes   = (const int*)d_in[1];
    const int* ys          = (const int*)d_in[2];
    const int* xs          = (const int*)d_in[3];
    const int* hs          = (const int*)d_in[4];
    const int* ws          = (const int*)d_in[5];
    float4* out            = (float4*)d_out;

    int total = BB * HH * W4;           // 4194304 threads
    int block = 256;
    int grid  = (total + block - 1) / block;  // 16384 blocks
    cutout_kernel<<<grid, block, 0, stream>>>(img, num_holes, ys, xs, hs, ws, out);
}